// Round 11
// baseline (1504.135 us; speedup 1.0000x reference)
//
#include <hip/hip_runtime.h>
#include <hip/hip_bf16.h>

// LSTM: S=512, B=128, I=256, H=512. Gates stacked (f,i,o,c) along dim0 of W/U.
// FP32 tensors; MFMA in bf16; epilogue/state fp32.
//
// Persistent cooperative kernel, 256 WGs x 256 thr, exchange via IF$ (sc0 sc1):
//   - 8 groups x 16 batch rows (grp = bid&7); 32 WGs/group x 16 H-cols.
//   - Waves = 4 K-quarters; disjoint 16x128 h slices; LDS partial planes.
//   - NEW vs round 10: TAGGED h cells (u32 = epoch<<16 | bf16). Producer
//     releases with NO vmcnt ack (h store -> flag store, both fire-and-forget).
//     Consumer: flag poll (cheap, bounds retries) -> tagged load -> validate
//     -> rare retry. Removes one full IF$ RTT from the release chain.

#define S_LEN 512
#define BATCH 128
#define ISZ   256
#define HSZ   512

typedef __attribute__((ext_vector_type(8))) short    s16x8;
typedef __attribute__((ext_vector_type(4))) float    f32x4;
typedef __attribute__((ext_vector_type(4))) unsigned u32x4;
typedef __attribute__((ext_vector_type(4))) int      i32x4;

#define FLAG_BYTES 4096
#define HOFF    4096
#define HXWORDS ((size_t)BATCH * HSZ)                // u32 words per slot
#define HXBYTES ((size_t)2 * BATCH * HSZ * 4)        // 512 KiB (2 parity slots)
#define XOFF    (HOFF + HXBYTES)
#define XBYTES  ((size_t)S_LEN * BATCH * ISZ * 2)    // 32 MiB
#define WS_NEED (XOFF + XBYTES)

__device__ __forceinline__ unsigned short f2bf(float f) {
    unsigned u = __float_as_uint(f);
    u += 0x7fffu + ((u >> 16) & 1u);                 // RNE
    return (unsigned short)(u >> 16);
}

__device__ __forceinline__ unsigned permb(unsigned a, unsigned b, unsigned sel) {
#if __has_builtin(__builtin_amdgcn_perm)
    return __builtin_amdgcn_perm(a, b, sel);
#else
    // generic fallback: sel 0x01000504 -> (b.lo16<<16)|a.lo16 ; 0x03020706 -> hi16s
    if (sel == 0x01000504u) return (a & 0xFFFFu) | (b << 16);
    else                    return (a >> 16) | (b & 0xFFFF0000u);
#endif
}

__device__ __forceinline__ s16x8 ld8f_bf(const float* p) {
    f32x4 a = *(const f32x4*)p;
    f32x4 b = *(const f32x4*)(p + 4);
    s16x8 r;
    r[0] = (short)f2bf(a[0]); r[1] = (short)f2bf(a[1]);
    r[2] = (short)f2bf(a[2]); r[3] = (short)f2bf(a[3]);
    r[4] = (short)f2bf(b[0]); r[5] = (short)f2bf(b[1]);
    r[6] = (short)f2bf(b[2]); r[7] = (short)f2bf(b[3]);
    return r;
}

__global__ void __launch_bounds__(256, 1)
cvt_x_kernel(const float* __restrict__ x, unsigned short* __restrict__ xbf, int n8) {
    int i = blockIdx.x * blockDim.x + threadIdx.x;
    const int stride = gridDim.x * blockDim.x;
    for (; i < n8; i += stride)
        *(s16x8*)(xbf + (size_t)i * 8) = ld8f_bf(x + (size_t)i * 8);
}

#define MFMA_BF16 __builtin_amdgcn_mfma_f32_16x16x32_bf16

template <bool BIGWS>
__global__ void __launch_bounds__(256, 1)
lstm_tagflag(const float* __restrict__ x,
             const float* __restrict__ W,
             const float* __restrict__ bW,
             const float* __restrict__ U,
             const float* __restrict__ bU,
             float* __restrict__ out,
             unsigned char* __restrict__ ws)
{
    __shared__ float g_lds[2][4][16][68];            // [parity][K-quarter][row][gcol]

    const int tid  = threadIdx.x;
    const int bid  = blockIdx.x;
    const int grp  = bid & 7;                        // 8 groups of 16 batch rows
    const int wg   = bid >> 3;                       // 32 WGs per group
    const int jBase = wg * 16;                       // H-col base
    const int rBase = grp * 16;                      // batch-row base

    unsigned* flags = (unsigned*)ws;                 // [grp][wg][wave]
    unsigned* hx    = (unsigned*)(ws + HOFF);        // tagged cells, 2 slots
    const unsigned short* xbf = (const unsigned short*)(ws + XOFF);

    // ---- wave geometry: wv = K-quarter ----
    const int kq   = tid >> 6;
    const int lane = tid & 63;
    const int l15  = lane & 15;
    const int lq   = lane >> 4;                      // k sub-group 0..3
    const int arow = rBase + l15;                    // batch row of A fragments

    // ---- step-invariant B fragments: 4 gate-tiles x own K-quarter ----
    s16x8 ub[4][4], wb[4][2];
    float bias[4];
    #pragma unroll
    for (int n = 0; n < 4; ++n) {
        const int gRow = n * HSZ + jBase + l15;
        bias[n] = (kq == 0) ? (bW[gRow] + bU[gRow]) : 0.f;
        #pragma unroll
        for (int ki = 0; ki < 4; ++ki)
            ub[n][ki] = ld8f_bf(U + (size_t)gRow * HSZ + kq * 128 + ki * 32 + lq * 8);
        #pragma unroll
        for (int ki = 0; ki < 2; ++ki)
            wb[n][ki] = ld8f_bf(W + (size_t)gRow * ISZ + kq * 64 + ki * 32 + lq * 8);
    }

    // ---- epilogue mapping: 256 threads x 1 cell (16 rows x 16 H-cols) ----
    const int er = tid >> 4, ej = tid & 15;
    const int orow = rBase + er, ocol = jBase + ej;
    float cst = 0.f;

    for (int t = 0; t < S_LEN; ++t) {
        const int par = t & 1;
        f32x4 acc[4] = { { bias[0], bias[0], bias[0], bias[0] },
                         { bias[1], bias[1], bias[1], bias[1] },
                         { bias[2], bias[2], bias[2], bias[2] },
                         { bias[3], bias[3], bias[3], bias[3] } };

        // x @ W^T (own K-quarter of I=256)
        #pragma unroll
        for (int ki = 0; ki < 2; ++ki) {
            s16x8 a;
            if constexpr (BIGWS)
                a = *(const s16x8*)(xbf + ((size_t)t * BATCH + arow) * ISZ
                                    + kq * 64 + ki * 32 + lq * 8);
            else
                a = ld8f_bf(x + ((size_t)t * BATCH + arow) * ISZ
                            + kq * 64 + ki * 32 + lq * 8);
            #pragma unroll
            for (int n = 0; n < 4; ++n)
                acc[n] = MFMA_BF16(a, wb[n][ki], acc[n], 0, 0, 0);
        }

        if (t > 0) {
            // ---- flag poll: producers of h cols [kq*128, kq*128+128)
            //      = WGs [kq*8, kq*8+8), waves 0..3 -> flags [kq*32, kq*32+32)
            const unsigned* fp = flags + grp * 128 + kq * 32 + (lane & 31);
            const unsigned tgt = (unsigned)t;
            for (;;) {
                unsigned v;
                asm volatile("global_load_dword %0, %1, off sc0 sc1\n\t"
                             "s_waitcnt vmcnt(0)" : "=v"(v) : "v"(fp) : "memory");
                if (__all(v >= tgt)) break;
            }
            __builtin_amdgcn_sched_barrier(0);

            // ---- tagged h load (own disjoint 16x128 slice; 32 u32 cells/lane) ----
            const unsigned* hp = hx + (size_t)((t - 1) & 1) * HXWORDS
                                 + (size_t)arow * HSZ + kq * 128 + lq * 8;
            const unsigned tt = ((unsigned)t << 16) | (unsigned)t;
            u32x4 L0, L1, L2, L3, L4, L5, L6, L7;
            for (;;) {
#define LDT(d, o) asm volatile("global_load_dwordx4 %0, %1, off offset:" o " sc0 sc1" \
                               : "=v"(d) : "v"(hp) : "memory")
                LDT(L0, "0");   LDT(L1, "16");
                LDT(L2, "128"); LDT(L3, "144");
                LDT(L4, "256"); LDT(L5, "272");
                LDT(L6, "384"); LDT(L7, "400");
#undef LDT
                asm volatile("s_waitcnt vmcnt(0)" ::: "memory");
                __builtin_amdgcn_sched_barrier(0);
                unsigned bad = 0;
#define TCHK(A) { bad |= permb(A[0], A[1], 0x03020706u) ^ tt; \
                  bad |= permb(A[2], A[3], 0x03020706u) ^ tt; }
                TCHK(L0) TCHK(L1) TCHK(L2) TCHK(L3)
                TCHK(L4) TCHK(L5) TCHK(L6) TCHK(L7)
#undef TCHK
                if (__all(bad == 0)) break;          // expected: first try
                __builtin_amdgcn_s_sleep(1);
            }

            // ---- pack payload (low16 of each cell) into A fragments ----
#define PACK(A, B) __builtin_bit_cast(s16x8, (i32x4){ \
        (int)permb(A[0], A[1], 0x01000504u), (int)permb(A[2], A[3], 0x01000504u), \
        (int)permb(B[0], B[1], 0x01000504u), (int)permb(B[2], B[3], 0x01000504u) })
            s16x8 f0 = PACK(L0, L1), f1 = PACK(L2, L3);
            s16x8 f2 = PACK(L4, L5), f3 = PACK(L6, L7);
#undef PACK
            #pragma unroll
            for (int n = 0; n < 4; ++n)
                acc[n] = MFMA_BF16(f0, ub[n][0], acc[n], 0, 0, 0);
            #pragma unroll
            for (int n = 0; n < 4; ++n)
                acc[n] = MFMA_BF16(f1, ub[n][1], acc[n], 0, 0, 0);
            #pragma unroll
            for (int n = 0; n < 4; ++n)
                acc[n] = MFMA_BF16(f2, ub[n][2], acc[n], 0, 0, 0);
            #pragma unroll
            for (int n = 0; n < 4; ++n)
                acc[n] = MFMA_BF16(f3, ub[n][3], acc[n], 0, 0, 0);
        }

        // ---- write K-quarter partials to own plane ----
        #pragma unroll
        for (int n = 0; n < 4; ++n)
            #pragma unroll
            for (int r = 0; r < 4; ++r)
                g_lds[par][kq][lq * 4 + r][n * 16 + l15] = acc[n][r];
        __syncthreads();                              // the ONLY intra-step sync

        // ---- epilogue: all 256 threads, one cell each; sum 4 K-planes ----
        const float gf = g_lds[par][0][er][ej]      + g_lds[par][1][er][ej]
                       + g_lds[par][2][er][ej]      + g_lds[par][3][er][ej];
        const float gi = g_lds[par][0][er][16 + ej] + g_lds[par][1][er][16 + ej]
                       + g_lds[par][2][er][16 + ej] + g_lds[par][3][er][16 + ej];
        const float go = g_lds[par][0][er][32 + ej] + g_lds[par][1][er][32 + ej]
                       + g_lds[par][2][er][32 + ej] + g_lds[par][3][er][32 + ej];
        const float gc = g_lds[par][0][er][48 + ej] + g_lds[par][1][er][48 + ej]
                       + g_lds[par][2][er][48 + ej] + g_lds[par][3][er][48 + ej];

        const float fg = 1.f / (1.f + __expf(-gf));
        const float ig = 1.f / (1.f + __expf(-gi));
        const float og = 1.f / (1.f + __expf(-go));
        const float ec = __expf(-2.f * fabsf(gc));
        const float cd = copysignf((1.f - ec) / (1.f + ec), gc);
        cst = fg * cst + ig * cd;
        const float eh = __expf(-2.f * fabsf(cst));
        const float hn = og * copysignf((1.f - eh) / (1.f + eh), cst);

        if (t < S_LEN - 1) {
            // fire-and-forget tagged publish (no ack), then per-wave flag
            unsigned hv = ((unsigned)(t + 1) << 16) | (unsigned)f2bf(hn);
            unsigned* hd = hx + (size_t)par * HXWORDS + (size_t)orow * HSZ + ocol;
            asm volatile("global_store_dword %0, %1, off sc0 sc1"
                         :: "v"(hd), "v"(hv) : "memory");
            if (lane == 0) {
                unsigned* fl = flags + grp * 128 + wg * 4 + kq;
                unsigned ep = (unsigned)(t + 1);
                asm volatile("global_store_dword %0, %1, off sc0 sc1"
                             :: "v"(fl), "v"(ep) : "memory");
            }
            out[((size_t)t * BATCH + orow) * HSZ + ocol] = hn;   // h_seq, off-path
        } else {
            out[((size_t)t * BATCH + orow) * HSZ + ocol] = hn;
            const size_t HSEQ = (size_t)S_LEN * BATCH * HSZ;
            out[HSEQ + (size_t)orow * HSZ + ocol] = hn;          // h_final
            out[HSEQ + (size_t)BATCH * HSZ + (size_t)orow * HSZ + ocol] = cst; // c_final
        }
    }
}

extern "C" void kernel_launch(void* const* d_in, const int* in_sizes, int n_in,
                              void* d_out, int out_size, void* d_ws, size_t ws_size,
                              hipStream_t stream) {
    const float* x  = (const float*)d_in[0];
    const float* W  = (const float*)d_in[1];
    const float* bW = (const float*)d_in[2];
    const float* U  = (const float*)d_in[3];
    const float* bU = (const float*)d_in[4];
    float* out = (float*)d_out;
    unsigned char* ws = (unsigned char*)d_ws;

    // flags AND tagged h slots must be zero every launch (stale tags from a
    // previous replay could alias epochs; ws is NOT re-poisoned between replays)
    hipMemsetAsync(ws, 0, HOFF + HXBYTES, stream);

    void* args[] = { (void*)&x, (void*)&W, (void*)&bW, (void*)&U, (void*)&bU,
                     (void*)&out, (void*)&ws };

    if (ws_size >= WS_NEED) {
        const int n8 = S_LEN * BATCH * ISZ / 8;
        cvt_x_kernel<<<2048, 256, 0, stream>>>(x, (unsigned short*)(ws + XOFF), n8);
        hipError_t e = hipLaunchCooperativeKernel((void*)lstm_tagflag<true>, dim3(256),
                                                  dim3(256), args, 0, stream);
        if (e != hipSuccess)
            lstm_tagflag<true><<<dim3(256), dim3(256), 0, stream>>>(x, W, bW, U, bU, out, ws);
    } else {
        hipError_t e = hipLaunchCooperativeKernel((void*)lstm_tagflag<false>, dim3(256),
                                                  dim3(256), args, 0, stream);
        if (e != hipSuccess)
            lstm_tagflag<false><<<dim3(256), dim3(256), 0, stream>>>(x, W, bW, U, bU, out, ws);
    }
}

// Round 13
// 1291.611 us; speedup vs baseline: 1.1645x; 1.1645x over previous
//
#include <hip/hip_runtime.h>
#include <hip/hip_bf16.h>

// LSTM: S=512, B=128, I=256, H=512. Gates stacked (f,i,o,c) along dim0 of W/U.
// FP32 tensors; MFMA in bf16; epilogue/state fp32.
//
// Persistent cooperative kernel, 256 WGs x 256 thr, ALL exchange sc0 sc1 (IF$):
//   - 8 groups x 16 batch rows (grp = bid&7); 32 WGs/group x 16 H-cols.
//   - Waves = 4 K-quarters; disjoint 16x128 h slices; 4 LDS partial planes.
//   - Per-wave flag release (h store -> vmcnt(0) -> flag), per-wave poll.
//   - Round-13 deltas vs round 10 (structure/protocol IDENTICAL):
//     * all inline-asm load outputs use "=&v" (early-clobber) -- round 12's
//       crash was output/address register aliasing with plain "=v";
//     * v_rcp_f32 for the 5 sigmoid/tanh denominators (~1 ulp, bf16-invisible).

#define S_LEN 512
#define BATCH 128
#define ISZ   256
#define HSZ   512

typedef __attribute__((ext_vector_type(8))) short  s16x8;
typedef __attribute__((ext_vector_type(4))) float  f32x4;

#define FLAG_BYTES 4096                              // 8 groups x 128 flags x 4B
#define HOFF   4096
#define HBYTES ((size_t)2 * BATCH * HSZ * 2)         // 256 KiB (2 parity slots)
#define XOFF   (HOFF + HBYTES)
#define XBYTES ((size_t)S_LEN * BATCH * ISZ * 2)     // 32 MiB
#define WS_NEED (XOFF + XBYTES)

__device__ __forceinline__ unsigned short f2bf(float f) {
    unsigned u = __float_as_uint(f);
    u += 0x7fffu + ((u >> 16) & 1u);                 // RNE
    return (unsigned short)(u >> 16);
}

__device__ __forceinline__ s16x8 ld8f_bf(const float* p) {
    f32x4 a = *(const f32x4*)p;
    f32x4 b = *(const f32x4*)(p + 4);
    s16x8 r;
    r[0] = (short)f2bf(a[0]); r[1] = (short)f2bf(a[1]);
    r[2] = (short)f2bf(a[2]); r[3] = (short)f2bf(a[3]);
    r[4] = (short)f2bf(b[0]); r[5] = (short)f2bf(b[1]);
    r[6] = (short)f2bf(b[2]); r[7] = (short)f2bf(b[3]);
    return r;
}

__global__ void __launch_bounds__(256, 1)
cvt_x_kernel(const float* __restrict__ x, unsigned short* __restrict__ xbf, int n8) {
    int i = blockIdx.x * blockDim.x + threadIdx.x;
    const int stride = gridDim.x * blockDim.x;
    for (; i < n8; i += stride)
        *(s16x8*)(xbf + (size_t)i * 8) = ld8f_bf(x + (size_t)i * 8);
}

#define MFMA_BF16 __builtin_amdgcn_mfma_f32_16x16x32_bf16

template <bool BIGWS>
__global__ void __launch_bounds__(256, 1)
lstm_kq3(const float* __restrict__ x,
         const float* __restrict__ W,
         const float* __restrict__ bW,
         const float* __restrict__ U,
         const float* __restrict__ bU,
         float* __restrict__ out,
         unsigned char* __restrict__ ws)
{
    __shared__ float g_lds[2][4][16][68];            // [parity][K-quarter][row][gcol]

    const int tid  = threadIdx.x;
    const int bid  = blockIdx.x;
    const int grp  = bid & 7;                        // 8 groups of 16 batch rows
    const int wg   = bid >> 3;                       // 32 WGs per group
    const int jBase = wg * 16;                       // H-col base
    const int rBase = grp * 16;                      // batch-row base

    unsigned* flags = (unsigned*)ws;                 // [grp][wg][wave]
    unsigned short* h0 = (unsigned short*)(ws + HOFF);
    unsigned short* h1 = h0 + BATCH * HSZ;
    const unsigned short* xbf = (const unsigned short*)(ws + XOFF);

    // ---- wave geometry: wv = K-quarter ----
    const int kq   = tid >> 6;
    const int lane = tid & 63;
    const int l15  = lane & 15;
    const int lq   = lane >> 4;                      // k sub-group 0..3
    const int arow = rBase + l15;                    // batch row of A fragments

    // ---- step-invariant B fragments: 4 gate-tiles x own K-quarter ----
    s16x8 ub[4][4], wb[4][2];
    float bias[4];
    #pragma unroll
    for (int n = 0; n < 4; ++n) {
        const int gRow = n * HSZ + jBase + l15;
        bias[n] = (kq == 0) ? (bW[gRow] + bU[gRow]) : 0.f;
        #pragma unroll
        for (int ki = 0; ki < 4; ++ki)
            ub[n][ki] = ld8f_bf(U + (size_t)gRow * HSZ + kq * 128 + ki * 32 + lq * 8);
        #pragma unroll
        for (int ki = 0; ki < 2; ++ki)
            wb[n][ki] = ld8f_bf(W + (size_t)gRow * ISZ + kq * 64 + ki * 32 + lq * 8);
    }

    // ---- epilogue mapping: 256 threads x 1 cell (16 rows x 16 H-cols) ----
    const int er = tid >> 4, ej = tid & 15;
    const int orow = rBase + er, ocol = jBase + ej;
    float cst = 0.f;

    for (int t = 0; t < S_LEN; ++t) {
        const int par = t & 1;
        f32x4 acc[4] = { { bias[0], bias[0], bias[0], bias[0] },
                         { bias[1], bias[1], bias[1], bias[1] },
                         { bias[2], bias[2], bias[2], bias[2] },
                         { bias[3], bias[3], bias[3], bias[3] } };

        // x @ W^T (own K-quarter of I=256) -- overlaps other WGs' release tails
        #pragma unroll
        for (int ki = 0; ki < 2; ++ki) {
            s16x8 a;
            if constexpr (BIGWS)
                a = *(const s16x8*)(xbf + ((size_t)t * BATCH + arow) * ISZ
                                    + kq * 64 + ki * 32 + lq * 8);
            else
                a = ld8f_bf(x + ((size_t)t * BATCH + arow) * ISZ
                            + kq * 64 + ki * 32 + lq * 8);
            #pragma unroll
            for (int n = 0; n < 4; ++n)
                acc[n] = MFMA_BF16(a, wb[n][ki], acc[n], 0, 0, 0);
        }

        if (t > 0) {
            // ---- per-wave poll: producers of h cols [kq*128, kq*128+128)
            //      = WGs [kq*8, kq*8+8), waves 0..3 -> flags [kq*32, kq*32+32)
            const unsigned* fp = flags + grp * 128 + kq * 32 + (lane & 31);
            const unsigned tgt = (unsigned)t;
            for (;;) {
                unsigned v;
                asm volatile("global_load_dword %0, %1, off sc0 sc1\n\t"
                             "s_waitcnt vmcnt(0)"
                             : "=&v"(v) : "v"(fp) : "memory");
                if (__all(v >= tgt)) break;
            }
            __builtin_amdgcn_sched_barrier(0);

            // ---- h_{t-1} A-fragments: own disjoint 16x128 slice (4 loads) ----
            const unsigned short* hp = (par ? h0 : h1)
                                       + (size_t)arow * HSZ + kq * 128 + lq * 8;
            s16x8 f0, f1, f2, f3;
#define LDH(d, o) asm volatile("global_load_dwordx4 %0, %1, off offset:" o " sc0 sc1" \
                               : "=&v"(d) : "v"(hp) : "memory")
            LDH(f0, "0"); LDH(f1, "64"); LDH(f2, "128"); LDH(f3, "192");
#undef LDH
            asm volatile("s_waitcnt vmcnt(2)" ::: "memory");
            __builtin_amdgcn_sched_barrier(0);
            #pragma unroll
            for (int n = 0; n < 4; ++n)
                acc[n] = MFMA_BF16(f0, ub[n][0], acc[n], 0, 0, 0);
            #pragma unroll
            for (int n = 0; n < 4; ++n)
                acc[n] = MFMA_BF16(f1, ub[n][1], acc[n], 0, 0, 0);
            asm volatile("s_waitcnt vmcnt(0)" ::: "memory");
            __builtin_amdgcn_sched_barrier(0);
            #pragma unroll
            for (int n = 0; n < 4; ++n)
                acc[n] = MFMA_BF16(f2, ub[n][2], acc[n], 0, 0, 0);
            #pragma unroll
            for (int n = 0; n < 4; ++n)
                acc[n] = MFMA_BF16(f3, ub[n][3], acc[n], 0, 0, 0);
        }

        // ---- write K-quarter partials to own plane ----
        #pragma unroll
        for (int n = 0; n < 4; ++n)
            #pragma unroll
            for (int r = 0; r < 4; ++r)
                g_lds[par][kq][lq * 4 + r][n * 16 + l15] = acc[n][r];
        __syncthreads();                              // the ONLY intra-step sync

        // ---- epilogue: all 256 threads, one cell each; sum 4 K-planes ----
        const float gf = g_lds[par][0][er][ej]      + g_lds[par][1][er][ej]
                       + g_lds[par][2][er][ej]      + g_lds[par][3][er][ej];
        const float gi = g_lds[par][0][er][16 + ej] + g_lds[par][1][er][16 + ej]
                       + g_lds[par][2][er][16 + ej] + g_lds[par][3][er][16 + ej];
        const float go = g_lds[par][0][er][32 + ej] + g_lds[par][1][er][32 + ej]
                       + g_lds[par][2][er][32 + ej] + g_lds[par][3][er][32 + ej];
        const float gc = g_lds[par][0][er][48 + ej] + g_lds[par][1][er][48 + ej]
                       + g_lds[par][2][er][48 + ej] + g_lds[par][3][er][48 + ej];

        // v_rcp_f32 denominators (~1 ulp; outputs are bf16-rounded anyway)
        const float fg = __builtin_amdgcn_rcpf(1.f + __expf(-gf));
        const float ig = __builtin_amdgcn_rcpf(1.f + __expf(-gi));
        const float og = __builtin_amdgcn_rcpf(1.f + __expf(-go));
        const float ec = __expf(-2.f * fabsf(gc));
        const float cd = copysignf((1.f - ec) * __builtin_amdgcn_rcpf(1.f + ec), gc);
        cst = fg * cst + ig * cd;
        const float eh = __expf(-2.f * fabsf(cst));
        const float hn = og * copysignf((1.f - eh) * __builtin_amdgcn_rcpf(1.f + eh), cst);

        if (t < S_LEN - 1) {
            // publish h_t -> IF$, ack own wave's stores, then per-wave flag
            unsigned hv = (unsigned)f2bf(hn);
            unsigned short* hd = (par ? h1 : h0) + (size_t)orow * HSZ + ocol;
            asm volatile("global_store_short %0, %1, off sc0 sc1"
                         :: "v"(hd), "v"(hv) : "memory");
            asm volatile("s_waitcnt vmcnt(0)" ::: "memory");
            if (lane == 0) {
                unsigned* fl = flags + grp * 128 + wg * 4 + kq;
                unsigned ep = (unsigned)(t + 1);
                asm volatile("global_store_dword %0, %1, off sc0 sc1"
                             :: "v"(fl), "v"(ep) : "memory");
            }
            out[((size_t)t * BATCH + orow) * HSZ + ocol] = hn;   // h_seq, off-path
        } else {
            out[((size_t)t * BATCH + orow) * HSZ + ocol] = hn;
            const size_t HSEQ = (size_t)S_LEN * BATCH * HSZ;
            out[HSEQ + (size_t)orow * HSZ + ocol] = hn;          // h_final
            out[HSEQ + (size_t)BATCH * HSZ + (size_t)orow * HSZ + ocol] = cst; // c_final
        }
    }
}

extern "C" void kernel_launch(void* const* d_in, const int* in_sizes, int n_in,
                              void* d_out, int out_size, void* d_ws, size_t ws_size,
                              hipStream_t stream) {
    const float* x  = (const float*)d_in[0];
    const float* W  = (const float*)d_in[1];
    const float* bW = (const float*)d_in[2];
    const float* U  = (const float*)d_in[3];
    const float* bU = (const float*)d_in[4];
    float* out = (float*)d_out;
    unsigned char* ws = (unsigned char*)d_ws;

    // per-wave epoch flags must be 0 at every launch (ws not re-poisoned)
    hipMemsetAsync(ws, 0, FLAG_BYTES, stream);

    void* args[] = { (void*)&x, (void*)&W, (void*)&bW, (void*)&U, (void*)&bU,
                     (void*)&out, (void*)&ws };

    if (ws_size >= WS_NEED) {
        const int n8 = S_LEN * BATCH * ISZ / 8;
        cvt_x_kernel<<<2048, 256, 0, stream>>>(x, (unsigned short*)(ws + XOFF), n8);
        hipError_t e = hipLaunchCooperativeKernel((void*)lstm_kq3<true>, dim3(256),
                                                  dim3(256), args, 0, stream);
        if (e != hipSuccess)
            lstm_kq3<true><<<dim3(256), dim3(256), 0, stream>>>(x, W, bW, U, bU, out, ws);
    } else {
        hipError_t e = hipLaunchCooperativeKernel((void*)lstm_kq3<false>, dim3(256),
                                                  dim3(256), args, 0, stream);
        if (e != hipSuccess)
            lstm_kq3<false><<<dim3(256), dim3(256), 0, stream>>>(x, W, bW, U, bU, out, ws);
    }
}

// Round 15
// 1275.373 us; speedup vs baseline: 1.1794x; 1.0127x over previous
//
#include <hip/hip_runtime.h>
#include <hip/hip_bf16.h>

// LSTM: S=512, B=128, I=256, H=512. Gates stacked (f,i,o,c) along dim0 of W/U.
// FP32 tensors; MFMA in bf16; epilogue/state fp32.
//
// Persistent cooperative kernel, 256 WGs x 256 thr, ALL exchange sc0 sc1 (IF$):
//   - 8 groups x 16 batch rows (grp = bid&7); 32 WGs/group x 16 H-cols.
//   - Waves = 4 K-quarters; disjoint 16x128 h slices; 4 LDS partial planes.
//   - TRIPLE-buffered h slots (t%3): closes the 2-step-skew WAR race.
//     Writer@t+3 overwrites slot t%3 only after (2-hop flag chain) ALL waves
//     finished step t+1, i.e., after every reader's step-t+1 load of slot t%3.
//     (Round-14's marginal fail = this race, fired by the faster double-poll.)
//   - Pipelined double-poll (2 outstanding flag loads, vmcnt(1)) -- detect
//     period ~RTT/2. All asm load outputs "=&v" (round-12 lesson); exactly
//     one dangling poll load, drained by the h-load vmcnt(2); vA/vB pinned.
//   - Per-wave flag release (h store -> vmcnt(0) -> lane0 flag), v_rcp epilogue.

#define S_LEN 512
#define BATCH 128
#define ISZ   256
#define HSZ   512

typedef __attribute__((ext_vector_type(8))) short  s16x8;
typedef __attribute__((ext_vector_type(4))) float  f32x4;

#define FLAG_BYTES 4096                              // 8 groups x 128 flags x 4B
#define HOFF   4096
#define HBYTES ((size_t)3 * BATCH * HSZ * 2)         // 384 KiB (3 slots)
#define XOFF   (HOFF + HBYTES)
#define XBYTES ((size_t)S_LEN * BATCH * ISZ * 2)     // 32 MiB
#define WS_NEED (XOFF + XBYTES)

__device__ __forceinline__ unsigned short f2bf(float f) {
    unsigned u = __float_as_uint(f);
    u += 0x7fffu + ((u >> 16) & 1u);                 // RNE
    return (unsigned short)(u >> 16);
}

__device__ __forceinline__ s16x8 ld8f_bf(const float* p) {
    f32x4 a = *(const f32x4*)p;
    f32x4 b = *(const f32x4*)(p + 4);
    s16x8 r;
    r[0] = (short)f2bf(a[0]); r[1] = (short)f2bf(a[1]);
    r[2] = (short)f2bf(a[2]); r[3] = (short)f2bf(a[3]);
    r[4] = (short)f2bf(b[0]); r[5] = (short)f2bf(b[1]);
    r[6] = (short)f2bf(b[2]); r[7] = (short)f2bf(b[3]);
    return r;
}

__global__ void __launch_bounds__(256, 1)
cvt_x_kernel(const float* __restrict__ x, unsigned short* __restrict__ xbf, int n8) {
    int i = blockIdx.x * blockDim.x + threadIdx.x;
    const int stride = gridDim.x * blockDim.x;
    for (; i < n8; i += stride)
        *(s16x8*)(xbf + (size_t)i * 8) = ld8f_bf(x + (size_t)i * 8);
}

#define MFMA_BF16 __builtin_amdgcn_mfma_f32_16x16x32_bf16

template <bool BIGWS>
__global__ void __launch_bounds__(256, 1)
lstm_kq5(const float* __restrict__ x,
         const float* __restrict__ W,
         const float* __restrict__ bW,
         const float* __restrict__ U,
         const float* __restrict__ bU,
         float* __restrict__ out,
         unsigned char* __restrict__ ws)
{
    __shared__ float g_lds[2][4][16][68];            // [parity][K-quarter][row][gcol]

    const int tid  = threadIdx.x;
    const int bid  = blockIdx.x;
    const int grp  = bid & 7;                        // 8 groups of 16 batch rows
    const int wg   = bid >> 3;                       // 32 WGs per group
    const int jBase = wg * 16;                       // H-col base
    const int rBase = grp * 16;                      // batch-row base

    unsigned* flags = (unsigned*)ws;                 // [grp][wg][wave]
    unsigned short* hb = (unsigned short*)(ws + HOFF);   // 3 slots x 64K elems
    const unsigned short* xbf = (const unsigned short*)(ws + XOFF);

    // ---- wave geometry: wv = K-quarter ----
    const int kq   = tid >> 6;
    const int lane = tid & 63;
    const int l15  = lane & 15;
    const int lq   = lane >> 4;                      // k sub-group 0..3
    const int arow = rBase + l15;                    // batch row of A fragments

    // ---- step-invariant B fragments: 4 gate-tiles x own K-quarter ----
    s16x8 ub[4][4], wb[4][2];
    float bias[4];
    #pragma unroll
    for (int n = 0; n < 4; ++n) {
        const int gRow = n * HSZ + jBase + l15;
        bias[n] = (kq == 0) ? (bW[gRow] + bU[gRow]) : 0.f;
        #pragma unroll
        for (int ki = 0; ki < 4; ++ki)
            ub[n][ki] = ld8f_bf(U + (size_t)gRow * HSZ + kq * 128 + ki * 32 + lq * 8);
        #pragma unroll
        for (int ki = 0; ki < 2; ++ki)
            wb[n][ki] = ld8f_bf(W + (size_t)gRow * ISZ + kq * 64 + ki * 32 + lq * 8);
    }

    // ---- epilogue mapping: 256 threads x 1 cell (16 rows x 16 H-cols) ----
    const int er = tid >> 4, ej = tid & 15;
    const int orow = rBase + er, ocol = jBase + ej;
    float cst = 0.f;

    int wslot = 0, rslot = 2;                        // wslot = t%3, rslot = (t-1)%3

    for (int t = 0; t < S_LEN; ++t) {
        const int par = t & 1;
        f32x4 acc[4] = { { bias[0], bias[0], bias[0], bias[0] },
                         { bias[1], bias[1], bias[1], bias[1] },
                         { bias[2], bias[2], bias[2], bias[2] },
                         { bias[3], bias[3], bias[3], bias[3] } };

        // x @ W^T (own K-quarter of I=256) -- overlaps other WGs' release tails
        #pragma unroll
        for (int ki = 0; ki < 2; ++ki) {
            s16x8 a;
            if constexpr (BIGWS)
                a = *(const s16x8*)(xbf + ((size_t)t * BATCH + arow) * ISZ
                                    + kq * 64 + ki * 32 + lq * 8);
            else
                a = ld8f_bf(x + ((size_t)t * BATCH + arow) * ISZ
                            + kq * 64 + ki * 32 + lq * 8);
            #pragma unroll
            for (int n = 0; n < 4; ++n)
                acc[n] = MFMA_BF16(a, wb[n][ki], acc[n], 0, 0, 0);
        }

        if (t > 0) {
            // ---- pipelined double-poll: 2 outstanding flag loads, vmcnt(1) ----
            // producers of h cols [kq*128, kq*128+128) = WGs [kq*8, kq*8+8),
            // waves 0..3 -> flags [kq*32, kq*32+32)
            const unsigned* fp = flags + grp * 128 + kq * 32 + (lane & 31);
            const unsigned tgt = (unsigned)t;
            unsigned vA, vB;
            asm volatile("global_load_dword %0, %1, off sc0 sc1"
                         : "=&v"(vA) : "v"(fp) : "memory");
            asm volatile("global_load_dword %0, %1, off sc0 sc1"
                         : "=&v"(vB) : "v"(fp) : "memory");
            for (;;) {
                asm volatile("s_waitcnt vmcnt(1)" ::: "memory");   // oldest done
                __builtin_amdgcn_sched_barrier(0);
                if (__all(vA >= tgt)) break;
                asm volatile("global_load_dword %0, %1, off sc0 sc1"
                             : "=&v"(vA) : "v"(fp) : "memory");
                asm volatile("s_waitcnt vmcnt(1)" ::: "memory");
                __builtin_amdgcn_sched_barrier(0);
                if (__all(vB >= tgt)) break;
                asm volatile("global_load_dword %0, %1, off sc0 sc1"
                             : "=&v"(vB) : "v"(fp) : "memory");
            }
            // exactly one poll load still in flight; drained by vmcnt(2) below
            // (issue order: dangling, f0..f3). vA/vB pinned live past that.

            // ---- h_{t-1} A-fragments from slot rslot (own 16x128 slice) ----
            const unsigned short* hp = hb + (rslot << 16)
                                       + (size_t)arow * HSZ + kq * 128 + lq * 8;
            s16x8 f0, f1, f2, f3;
#define LDH(d, o) asm volatile("global_load_dwordx4 %0, %1, off offset:" o " sc0 sc1" \
                               : "=&v"(d) : "v"(hp) : "memory")
            LDH(f0, "0"); LDH(f1, "64"); LDH(f2, "128"); LDH(f3, "192");
#undef LDH
            asm volatile("s_waitcnt vmcnt(2)" ::: "memory");   // dangling+f0+f1 done
            __builtin_amdgcn_sched_barrier(0);
            asm volatile("" :: "v"(vA), "v"(vB));              // liveness pin
            #pragma unroll
            for (int n = 0; n < 4; ++n)
                acc[n] = MFMA_BF16(f0, ub[n][0], acc[n], 0, 0, 0);
            #pragma unroll
            for (int n = 0; n < 4; ++n)
                acc[n] = MFMA_BF16(f1, ub[n][1], acc[n], 0, 0, 0);
            asm volatile("s_waitcnt vmcnt(0)" ::: "memory");
            __builtin_amdgcn_sched_barrier(0);
            #pragma unroll
            for (int n = 0; n < 4; ++n)
                acc[n] = MFMA_BF16(f2, ub[n][2], acc[n], 0, 0, 0);
            #pragma unroll
            for (int n = 0; n < 4; ++n)
                acc[n] = MFMA_BF16(f3, ub[n][3], acc[n], 0, 0, 0);
        }

        // ---- write K-quarter partials to own plane ----
        #pragma unroll
        for (int n = 0; n < 4; ++n)
            #pragma unroll
            for (int r = 0; r < 4; ++r)
                g_lds[par][kq][lq * 4 + r][n * 16 + l15] = acc[n][r];
        __syncthreads();                              // the ONLY intra-step sync

        // ---- epilogue: all 256 threads, one cell each; sum 4 K-planes ----
        const float gf = g_lds[par][0][er][ej]      + g_lds[par][1][er][ej]
                       + g_lds[par][2][er][ej]      + g_lds[par][3][er][ej];
        const float gi = g_lds[par][0][er][16 + ej] + g_lds[par][1][er][16 + ej]
                       + g_lds[par][2][er][16 + ej] + g_lds[par][3][er][16 + ej];
        const float go = g_lds[par][0][er][32 + ej] + g_lds[par][1][er][32 + ej]
                       + g_lds[par][2][er][32 + ej] + g_lds[par][3][er][32 + ej];
        const float gc = g_lds[par][0][er][48 + ej] + g_lds[par][1][er][48 + ej]
                       + g_lds[par][2][er][48 + ej] + g_lds[par][3][er][48 + ej];

        // v_rcp_f32 denominators (~1 ulp; outputs are bf16-rounded anyway)
        const float fg = __builtin_amdgcn_rcpf(1.f + __expf(-gf));
        const float ig = __builtin_amdgcn_rcpf(1.f + __expf(-gi));
        const float og = __builtin_amdgcn_rcpf(1.f + __expf(-go));
        const float ec = __expf(-2.f * fabsf(gc));
        const float cd = copysignf((1.f - ec) * __builtin_amdgcn_rcpf(1.f + ec), gc);
        cst = fg * cst + ig * cd;
        const float eh = __expf(-2.f * fabsf(cst));
        const float hn = og * copysignf((1.f - eh) * __builtin_amdgcn_rcpf(1.f + eh), cst);

        if (t < S_LEN - 1) {
            // publish h_t into slot wslot -> IF$, ack, then per-wave flag
            unsigned hv = (unsigned)f2bf(hn);
            unsigned short* hd = hb + (wslot << 16) + (size_t)orow * HSZ + ocol;
            asm volatile("global_store_short %0, %1, off sc0 sc1"
                         :: "v"(hd), "v"(hv) : "memory");
            asm volatile("s_waitcnt vmcnt(0)" ::: "memory");
            if (lane == 0) {
                unsigned* fl = flags + grp * 128 + wg * 4 + kq;
                unsigned ep = (unsigned)(t + 1);
                asm volatile("global_store_dword %0, %1, off sc0 sc1"
                             :: "v"(fl), "v"(ep) : "memory");
            }
            out[((size_t)t * BATCH + orow) * HSZ + ocol] = hn;   // h_seq, off-path
        } else {
            out[((size_t)t * BATCH + orow) * HSZ + ocol] = hn;
            const size_t HSEQ = (size_t)S_LEN * BATCH * HSZ;
            out[HSEQ + (size_t)orow * HSZ + ocol] = hn;          // h_final
            out[HSEQ + (size_t)BATCH * HSZ + (size_t)orow * HSZ + ocol] = cst; // c_final
        }

        rslot = wslot;
        wslot = (wslot == 2) ? 0 : wslot + 1;
    }
}

extern "C" void kernel_launch(void* const* d_in, const int* in_sizes, int n_in,
                              void* d_out, int out_size, void* d_ws, size_t ws_size,
                              hipStream_t stream) {
    const float* x  = (const float*)d_in[0];
    const float* W  = (const float*)d_in[1];
    const float* bW = (const float*)d_in[2];
    const float* U  = (const float*)d_in[3];
    const float* bU = (const float*)d_in[4];
    float* out = (float*)d_out;
    unsigned char* ws = (unsigned char*)d_ws;

    // per-wave epoch flags must be 0 at every launch (ws not re-poisoned)
    hipMemsetAsync(ws, 0, FLAG_BYTES, stream);

    void* args[] = { (void*)&x, (void*)&W, (void*)&bW, (void*)&U, (void*)&bU,
                     (void*)&out, (void*)&ws };

    if (ws_size >= WS_NEED) {
        const int n8 = S_LEN * BATCH * ISZ / 8;
        cvt_x_kernel<<<2048, 256, 0, stream>>>(x, (unsigned short*)(ws + XOFF), n8);
        hipError_t e = hipLaunchCooperativeKernel((void*)lstm_kq5<true>, dim3(256),
                                                  dim3(256), args, 0, stream);
        if (e != hipSuccess)
            lstm_kq5<true><<<dim3(256), dim3(256), 0, stream>>>(x, W, bW, U, bU, out, ws);
    } else {
        hipError_t e = hipLaunchCooperativeKernel((void*)lstm_kq5<false>, dim3(256),
                                                  dim3(256), args, 0, stream);
        if (e != hipSuccess)
            lstm_kq5<false><<<dim3(256), dim3(256), 0, stream>>>(x, W, bW, U, bU, out, ws);
    }
}